// Round 9
// baseline (145.739 us; speedup 1.0000x reference)
//
#include <hip/hip_runtime.h>
#include <math.h>

typedef short bf16x8 __attribute__((ext_vector_type(8)));
typedef float f32x16 __attribute__((ext_vector_type(16)));
typedef float f32x4  __attribute__((ext_vector_type(4)));
typedef float f32x2  __attribute__((ext_vector_type(2)));
typedef unsigned int u32x4 __attribute__((ext_vector_type(4)));
typedef unsigned int u32x2 __attribute__((ext_vector_type(2)));

namespace {
constexpr int kNCont = 6, kNCat = 6, kNCategories = 100;
constexpr int kQ = 12, kD = 10, kHid = 20, kD0 = 10;
constexpr int kL1 = 30, kL2 = 20, kNPairs = 78;
constexpr int kM = 32;            // batch tile per block
constexpr int kBlock = 256;       // 4 waves
constexpr int kES = 6;            // u32 stride per [q][b] E slot (5 used + pad)
}

// Per-wave k ownership (partition of 0..11); pair counts 19/20/20/19.
__constant__ int cKset[12] = {11, 4, 1, 10, 5, 2, 9, 8, 0, 7, 6, 3};

union ABu { u32x4 u; bf16x8 s; unsigned int w[4]; unsigned short h[8]; };
union D16 { f32x16 v; f32x4 q[4]; float f[16]; };

__device__ __forceinline__ unsigned int fu(float x) { return __float_as_uint(x); }
__device__ __forceinline__ unsigned short f2bf_rne(float v) {
    unsigned int x = fu(v);
    return (unsigned short)((x + 0x7FFFu + ((x >> 16) & 1u)) >> 16);
}
// pack two f32 to bf16x2 by truncation: low16 = hi(e0), high16 = hi(e1)
__device__ __forceinline__ unsigned int pack_trunc(float e0, float e1) {
    return __builtin_amdgcn_perm(fu(e1), fu(e0), 0x07060302u);
}

// Embedding E[gb,q,:] as 5 f32x2. q is SCALAR. All register indices static.
__device__ __forceinline__ void compute_E(
    int q, int gb,
    const float* __restrict__ x_cont, const int* __restrict__ x_cat,
    const float* __restrict__ cont_W1, const float* __restrict__ cont_b1,
    const float* __restrict__ cont_W2, const float* __restrict__ cont_b2,
    const float* __restrict__ cat_tables, f32x2 E2[5])
{
    if (q < kNCont) {
        const float x = x_cont[gb * kNCont + q];
        #pragma unroll
        for (int dd = 0; dd < 5; ++dd)
            E2[dd] = f32x2{cont_b2[q * kD + 2 * dd], cont_b2[q * kD + 2 * dd + 1]};
        #pragma unroll
        for (int h = 0; h < kHid; ++h) {
            const float pre = fmaf(x, cont_W1[q * kHid + h], cont_b1[q * kHid + h]);
            const float hv  = fmaxf(pre, 0.0f);
            const f32x2 hv2 = {hv, hv};
            const float* w2 = cont_W2 + (q * kHid + h) * kD;
            #pragma unroll
            for (int dd = 0; dd < 5; ++dd)
                E2[dd] = __builtin_elementwise_fma(
                    hv2, f32x2{w2[2 * dd], w2[2 * dd + 1]}, E2[dd]);
        }
    } else {
        const int c   = q - kNCont;
        const int idx = x_cat[gb * kNCat + c];
        const float* src = cat_tables + (c * kNCategories + idx) * kD;
        #pragma unroll
        for (int dd = 0; dd < 5; ++dd)
            E2[dd] = f32x2{src[2 * dd], src[2 * dd + 1]};
    }
}

__global__ __launch_bounds__(kBlock, 6) void pin_main(
    const float* __restrict__ x_cont,
    const int*   __restrict__ x_cat,
    const float* __restrict__ exposure,
    const float* __restrict__ cont_W1,
    const float* __restrict__ cont_b1,
    const float* __restrict__ cont_W2,
    const float* __restrict__ cont_b2,
    const float* __restrict__ cat_tables,
    const float* __restrict__ tokens,  // [78,10]
    const float* __restrict__ sW1,     // [30,30]
    const float* __restrict__ sb1,     // [30]
    const float* __restrict__ sW2,     // [30,20]
    const float* __restrict__ sb2,     // [20]
    const float* __restrict__ sW3,     // [20]
    const float* __restrict__ sb3,     // [1]
    const float* __restrict__ out_w,   // [78]
    const float* __restrict__ out_b,   // [1]
    float* __restrict__ out)
{
    // Packed-bf16 E table: [q][b][kES u32] (5 used). 9216 B.
    __shared__ unsigned int Elds[kQ * kM * kES];
    // Pair bias in MFMA C-layout (r8-verified permutation). 9984 B.
    __shared__ float biasl[kNPairs * 32];
    __shared__ float etab[kM];
    __shared__ float etaConst;

    const int tid   = threadIdx.x;
    const int lane  = tid & 63;
    const int b     = lane & 31;          // batch row / MFMA col n
    const int ihalf = lane >> 5;          // fragment k-half selector
    const int wv    = __builtin_amdgcn_readfirstlane((int)(tid >> 6));
    const int gb    = blockIdx.x * kM + b;

    if (tid < kM) etab[tid] = 0.0f;
    if (tid == 0) {
        float s = 0.0f;
        #pragma unroll 1
        for (int p = 0; p < kNPairs; ++p) s += out_w[p];
        etaConst = out_b[0] + sb3[0] * (1.0f / 6.0f) * s;
    }

    // ---- in-block pair-bias table (C-layout): biasl[p*32 + reg + 16*ih] ----
    // value = biasarr[tau(m)], m = (reg&3)+8*(reg>>2)+4*ih;
    // biasarr[i<30] = sb1[i] + tokens[p]@sW1[20:30]; [30]=1 (sb2 injector); [31]=0.
    #pragma unroll 1
    for (int e = tid; e < kNPairs * 32; e += kBlock) {
        const int p = e >> 5, idx = e & 31;
        const int r = idx & 15, ih = idx >> 4;
        const int m = (r & 3) + 8 * (r >> 2) + 4 * ih;
        const int mq = (m >> 2) & 3;
        const int mtau = m + (mq == 1 ? 4 : (mq == 2 ? -4 : 0));
        float val;
        if (mtau < kL1) {
            val = sb1[mtau];
            #pragma unroll
            for (int d = 0; d < kD0; ++d)
                val = fmaf(tokens[p * kD0 + d], sW1[(2 * kD + d) * kL1 + mtau], val);
        } else {
            val = (mtau == 30) ? 1.0f : 0.0f;
        }
        biasl[e] = val;
    }

    // tau: verified r7/r8 — C-reg order <-> i order for B-frag consumption.
    const int q2  = (b >> 2) & 3;
    const int tau = b + (q2 == 1 ? 4 : (q2 == 2 ? -4 : 0));

    // ---- stacked [W1a;W1b] A-frags: A[m][s] = sW1[s][tau(m)], s<20 ----
    ABu wab0, wab1;
    wab0.u = u32x4{0, 0, 0, 0};
    wab1.u = u32x4{0, 0, 0, 0};
    #pragma unroll
    for (int e = 0; e < 8; ++e) {         // kstep0: s = 8*ihalf + e (0..15)
        const int s = 8 * ihalf + e;
        wab0.h[e] = f2bf_rne((tau < kL1) ? sW1[s * kL1 + tau] : 0.0f);
    }
    if (ihalf == 0) {                      // kstep1: s = 16..19 live, rest 0
        #pragma unroll
        for (int e = 0; e < 4; ++e)
            wab1.h[e] = f2bf_rne((tau < kL1) ? sW1[(16 + e) * kL1 + tau] : 0.0f);
    }

    // ---- layer-2 A-frags (sW2 rows o=b, k-slots i; i=30 -> sb2) ----
    ABu bf0, bf1;
    #pragma unroll
    for (int e = 0; e < 8; ++e) {
        const int k0 = ihalf * 8 + e;
        const int k1 = 16 + ihalf * 8 + e;
        float v0 = 0.0f, v1 = 0.0f;
        if (b < kL2) {
            v0 = (k0 < kL1) ? sW2[k0 * kL2 + b] : (k0 == 30 ? sb2[b] : 0.0f);
            v1 = (k1 < kL1) ? sW2[k1 * kL2 + b] : (k1 == 30 ? sb2[b] : 0.0f);
        }
        bf0.h[e] = f2bf_rne(v0);
        bf1.h[e] = f2bf_rne(v1);
    }

    // ---- Phase A: wave computes E for its 3 q's, shares packed bf16 via LDS ----
    #pragma unroll 1
    for (int jj = 0; jj < 3; ++jj) {
        const int q = wv * 3 + jj;                    // scalar
        f32x2 E2[5];
        compute_E(q, gb, x_cont, x_cat, cont_W1, cont_b1, cont_W2, cont_b2,
                  cat_tables, E2);
        const unsigned int ep0 = pack_trunc(E2[0].x, E2[0].y);
        const unsigned int ep1 = pack_trunc(E2[1].x, E2[1].y);
        const unsigned int ep2 = pack_trunc(E2[2].x, E2[2].y);
        const unsigned int ep3 = pack_trunc(E2[3].x, E2[3].y);
        const unsigned int ep4 = pack_trunc(E2[4].x, E2[4].y);
        if (ihalf == 0) {                             // halves redundant; one writes
            unsigned int* dst = &Elds[(q * kM + b) * kES];
            *(u32x2*)(dst)     = u32x2{ep0, ep1};
            *(u32x2*)(dst + 2) = u32x2{ep2, ep3};
            dst[4] = ep4;
        }
    }
    __syncthreads();

    // ---- Phase B: pairs. h1 = [W1a;W1b]@[Ej;Ek] + bias in ONE MFMA chain ----
    f32x16 acc = {};
    const unsigned int* ebase = &Elds[b * kES];
    #pragma unroll 1
    for (int ki = 0; ki < 3; ++ki) {
        const int k = __builtin_amdgcn_readfirstlane(cKset[wv * 3 + ki]);
        const unsigned int* ekp = ebase + k * kM * kES;
        const u32x2 ek01 = *(const u32x2*)ekp;        // Ek (d01),(d23)
        const u32x2 ek23 = *(const u32x2*)(ekp + 2);  // (d45),(d67)
        const unsigned int ek4 = ekp[4];              // (d89)

        // e1 (kstep1 B-frag) constant per k: slots 16..19 = Ek d6..9
        ABu e1;
        if (ihalf == 0) e1.u = u32x4{ek23.y, ek4, 0u, 0u};
        else            e1.u = u32x4{0u, 0u, 0u, 0u};

        #pragma unroll 1
        for (int j = 0; j <= k; ++j) {
            const int p = j * kQ - (j * (j - 1)) / 2 + (k - j);
            const unsigned int* ejp = ebase + j * kM * kES;
            const u32x2 ej01 = *(const u32x2*)ejp;
            const u32x2 ej23 = *(const u32x2*)(ejp + 2);
            const unsigned int ej4 = ejp[4];

            // bias C-layout from LDS: per-half one address -> broadcast, free
            const float* bc = biasl + p * 32 + ihalf * 16;
            D16 cb;
            cb.q[0] = *(const f32x4*)bc;
            cb.q[1] = *(const f32x4*)(bc + 4);
            cb.q[2] = *(const f32x4*)(bc + 8);
            cb.q[3] = *(const f32x4*)(bc + 12);

            // B-frag kstep0: slots 0..9 = Ej d0..9, slots 10..15 = Ek d0..5
            ABu e0;
            if (ihalf == 0) e0.u = u32x4{ej01.x, ej01.y, ej23.x, ej23.y};
            else            e0.u = u32x4{ej4, ek01.x, ek01.y, ek23.x};

            f32x16 d1 = __builtin_amdgcn_mfma_f32_32x32x16_bf16(wab0.s, e0.s, cb.v, 0, 0, 0);
            d1 = __builtin_amdgcn_mfma_f32_32x32x16_bf16(wab1.s, e1.s, d1, 0, 0, 0);

            D16 t; t.v = __builtin_elementwise_max(d1, (f32x16){});
            ABu hf0, hf1;                              // h1 as layer-2 B-operand
            hf0.w[0] = pack_trunc(t.q[0].x, t.q[0].y);
            hf0.w[1] = pack_trunc(t.q[0].z, t.q[0].w);
            hf0.w[2] = pack_trunc(t.q[1].x, t.q[1].y);
            hf0.w[3] = pack_trunc(t.q[1].z, t.q[1].w);
            hf1.w[0] = pack_trunc(t.q[2].x, t.q[2].y);
            hf1.w[1] = pack_trunc(t.q[2].z, t.q[2].w);
            hf1.w[2] = pack_trunc(t.q[3].x, t.q[3].y);
            hf1.w[3] = pack_trunc(t.q[3].z, t.q[3].w);

            f32x16 d2 = {};
            d2 = __builtin_amdgcn_mfma_f32_32x32x16_bf16(bf0.s, hf0.s, d2, 0, 0, 0);
            d2 = __builtin_amdgcn_mfma_f32_32x32x16_bf16(bf1.s, hf1.s, d2, 0, 0, 0);

            const float wp = out_w[p];                 // s_load
            acc += __builtin_elementwise_max(d2, (f32x16){}) * wp;
        }
    }

    // ---- epilogue: eta[b] = (1/6)*sum_r sW3[o_r]*acc[r] ----
    float etaL = 0.0f;
    if (ihalf == 0) {       // r=0..11 -> o = 0..3, 8..11, 16..19
        #pragma unroll
        for (int r = 0; r < 12; ++r)
            etaL = fmaf(acc[r], sW3[(r & 3) + 8 * (r >> 2)], etaL);
    } else {                // r=0..7 -> o = 4..7, 12..15
        #pragma unroll
        for (int r = 0; r < 8; ++r)
            etaL = fmaf(acc[r], sW3[(r & 3) + 8 * (r >> 2) + 4], etaL);
    }
    etaL += __shfl_xor(etaL, 32, 64);   // combine o-halves
    if (ihalf == 0) atomicAdd(&etab[b], etaL);
    __syncthreads();

    if (tid < kM) {
        float eta = etab[tid] * (1.0f / 6.0f) + etaConst;
        eta = fminf(fmaxf(eta, -20.0f), 20.0f);
        const int ob = blockIdx.x * kM + tid;
        out[ob] = __expf(eta) * exposure[ob];
    }
}

extern "C" void kernel_launch(void* const* d_in, const int* in_sizes, int n_in,
                              void* d_out, int out_size, void* d_ws, size_t ws_size,
                              hipStream_t stream) {
    (void)n_in; (void)out_size; (void)d_ws; (void)ws_size;
    const float* x_cont     = (const float*)d_in[0];
    const int*   x_cat      = (const int*)  d_in[1];
    const float* exposure   = (const float*)d_in[2];
    const float* cont_W1    = (const float*)d_in[3];
    const float* cont_b1    = (const float*)d_in[4];
    const float* cont_W2    = (const float*)d_in[5];
    const float* cont_b2    = (const float*)d_in[6];
    const float* cat_tables = (const float*)d_in[7];
    const float* tokens     = (const float*)d_in[8];
    const float* sW1        = (const float*)d_in[9];
    const float* sb1        = (const float*)d_in[10];
    const float* sW2        = (const float*)d_in[11];
    const float* sb2        = (const float*)d_in[12];
    const float* sW3        = (const float*)d_in[13];
    const float* sb3        = (const float*)d_in[14];
    const float* out_w      = (const float*)d_in[15];
    const float* out_b      = (const float*)d_in[16];

    const int B = in_sizes[2];        // exposure is [B]
    pin_main<<<B / kM, kBlock, 0, stream>>>(
        x_cont, x_cat, exposure, cont_W1, cont_b1, cont_W2, cont_b2,
        cat_tables, tokens, sW1, sb1, sW2, sb2, sW3, sb3, out_w, out_b,
        (float*)d_out);
}

// Round 10
// 137.373 us; speedup vs baseline: 1.0609x; 1.0609x over previous
//
#include <hip/hip_runtime.h>
#include <math.h>

typedef short bf16x8 __attribute__((ext_vector_type(8)));
typedef float f32x16 __attribute__((ext_vector_type(16)));
typedef float f32x4  __attribute__((ext_vector_type(4)));
typedef float f32x2  __attribute__((ext_vector_type(2)));
typedef unsigned int u32x4 __attribute__((ext_vector_type(4)));
typedef unsigned int u32x2 __attribute__((ext_vector_type(2)));

namespace {
constexpr int kNCont = 6, kNCat = 6, kNCategories = 100;
constexpr int kQ = 12, kD = 10, kHid = 20, kD0 = 10;
constexpr int kL1 = 30, kL2 = 20, kNPairs = 78;
constexpr int kM = 32;            // batch tile per block
constexpr int kBlock = 256;       // 4 waves
constexpr int kES = 6;            // u32 stride per [q][b] E slot (5 used + pad)
}

// Per-wave k ownership (partition of 0..11); pair counts 19/20/20/19.
__constant__ int cKset[12] = {11, 4, 1, 10, 5, 2, 9, 8, 0, 7, 6, 3};

union ABu { u32x4 u; bf16x8 s; unsigned int w[4]; unsigned short h[8]; };
union D16 { f32x16 v; f32x4 q[4]; float f[16]; };

__device__ __forceinline__ unsigned int fu(float x) { return __float_as_uint(x); }
__device__ __forceinline__ unsigned short f2bf_rne(float v) {
    unsigned int x = fu(v);
    return (unsigned short)((x + 0x7FFFu + ((x >> 16) & 1u)) >> 16);
}
// pack two f32 to bf16x2 by truncation: low16 = hi(e0), high16 = hi(e1)
__device__ __forceinline__ unsigned int pack_trunc(float e0, float e1) {
    return __builtin_amdgcn_perm(fu(e1), fu(e0), 0x07060302u);
}

// Embedding E[gb,q,:] as 5 f32x2. q is SCALAR. All register indices static.
__device__ __forceinline__ void compute_E(
    int q, int gb,
    const float* __restrict__ x_cont, const int* __restrict__ x_cat,
    const float* __restrict__ cont_W1, const float* __restrict__ cont_b1,
    const float* __restrict__ cont_W2, const float* __restrict__ cont_b2,
    const float* __restrict__ cat_tables, f32x2 E2[5])
{
    if (q < kNCont) {
        const float x = x_cont[gb * kNCont + q];
        #pragma unroll
        for (int dd = 0; dd < 5; ++dd)
            E2[dd] = f32x2{cont_b2[q * kD + 2 * dd], cont_b2[q * kD + 2 * dd + 1]};
        #pragma unroll
        for (int h = 0; h < kHid; ++h) {
            const float pre = fmaf(x, cont_W1[q * kHid + h], cont_b1[q * kHid + h]);
            const float hv  = fmaxf(pre, 0.0f);
            const f32x2 hv2 = {hv, hv};
            const float* w2 = cont_W2 + (q * kHid + h) * kD;
            #pragma unroll
            for (int dd = 0; dd < 5; ++dd)
                E2[dd] = __builtin_elementwise_fma(
                    hv2, f32x2{w2[2 * dd], w2[2 * dd + 1]}, E2[dd]);
        }
    } else {
        const int c   = q - kNCont;
        const int idx = x_cat[gb * kNCat + c];
        const float* src = cat_tables + (c * kNCategories + idx) * kD;
        #pragma unroll
        for (int dd = 0; dd < 5; ++dd)
            E2[dd] = f32x2{src[2 * dd], src[2 * dd + 1]};
    }
}

__global__ __launch_bounds__(kBlock, 6) void pin_main(
    const float* __restrict__ x_cont,
    const int*   __restrict__ x_cat,
    const float* __restrict__ exposure,
    const float* __restrict__ cont_W1,
    const float* __restrict__ cont_b1,
    const float* __restrict__ cont_W2,
    const float* __restrict__ cont_b2,
    const float* __restrict__ cat_tables,
    const float* __restrict__ tokens,  // [78,10]
    const float* __restrict__ sW1,     // [30,30]
    const float* __restrict__ sb1,     // [30]
    const float* __restrict__ sW2,     // [30,20]
    const float* __restrict__ sb2,     // [20]
    const float* __restrict__ sW3,     // [20]
    const float* __restrict__ sb3,     // [1]
    const float* __restrict__ out_w,   // [78]
    const float* __restrict__ out_b,   // [1]
    float* __restrict__ out)
{
    // Packed-bf16 E table: [q][b][kES u32] (5 used). 9216 B.
    __shared__ unsigned int Elds[kQ * kM * kES];
    // Packed-bf16 tokens: [p][8 u32] (5 used; stride 8 for aligned b128). 2496 B.
    __shared__ unsigned int Tlds[kNPairs * 8];
    __shared__ float etab[kM];
    __shared__ float etaConst;

    const int tid   = threadIdx.x;
    const int lane  = tid & 63;
    const int b     = lane & 31;          // batch row / MFMA col n
    const int ihalf = lane >> 5;          // fragment k-half selector
    const int wv    = __builtin_amdgcn_readfirstlane((int)(tid >> 6));
    const int gb    = blockIdx.x * kM + b;

    if (tid < kM) etab[tid] = 0.0f;

    // ---- etaConst = out_b + sb3/6 * sum(out_w): parallel wave-0 reduce ----
    if (wv == 0) {
        float v = (lane < kNPairs) ? out_w[lane] : 0.0f;
        if (lane < kNPairs - 64) v += out_w[64 + lane];
        v += __shfl_xor(v, 1, 64);
        v += __shfl_xor(v, 2, 64);
        v += __shfl_xor(v, 4, 64);
        v += __shfl_xor(v, 8, 64);
        v += __shfl_xor(v, 16, 64);
        v += __shfl_xor(v, 32, 64);
        if (lane == 0) etaConst = out_b[0] + sb3[0] * (1.0f / 6.0f) * v;
    }

    // ---- packed-token table (coalesced; ~2 iters/thread) ----
    #pragma unroll 1
    for (int t = tid; t < kNPairs * 5; t += kBlock) {
        const int p = t / 5, dd = t - p * 5;
        Tlds[p * 8 + dd] =
            pack_trunc(tokens[p * kD0 + 2 * dd], tokens[p * kD0 + 2 * dd + 1]);
    }

    // tau: verified r7/r8 — C-reg order <-> i order for B-frag consumption.
    const int q2  = (b >> 2) & 3;
    const int tau = b + (q2 == 1 ? 4 : (q2 == 2 ? -4 : 0));

    // ---- stacked [W1a;W1b;W1c;sb1] A-frags: A[m][s] = sW1[s][tau(m)] ----
    // kstep0: s=0..15 (W1 rows 0..15). kstep1: s=16..31 (rows 16..29,
    // s=30 -> sb1[tau] with A[tau=30][30]=1 as layer-2 sb2-injector, s=31 -> 0).
    ABu wab0, wab1;
    #pragma unroll
    for (int e = 0; e < 8; ++e) {         // kstep0: s = 8*ihalf + e
        const int s = 8 * ihalf + e;
        wab0.h[e] = f2bf_rne((tau < kL1) ? sW1[s * kL1 + tau] : 0.0f);
    }
    #pragma unroll
    for (int e = 0; e < 8; ++e) {         // kstep1: s = 16 + 8*ihalf + e
        const int s = 16 + 8 * ihalf + e;
        float v = 0.0f;
        if (tau < kL1) {
            if (s < kL1)       v = sW1[s * kL1 + tau];
            else if (s == 30)  v = sb1[tau];
        } else if (tau == 30 && s == 30) {
            v = 1.0f;                      // h1 ones-row for layer-2 sb2
        }
        wab1.h[e] = f2bf_rne(v);
    }

    // ---- layer-2 A-frags (sW2 rows o=b, k-slots i; i=30 -> sb2) ----
    ABu bf0, bf1;
    #pragma unroll
    for (int e = 0; e < 8; ++e) {
        const int k0 = ihalf * 8 + e;
        const int k1 = 16 + ihalf * 8 + e;
        float v0 = 0.0f, v1 = 0.0f;
        if (b < kL2) {
            v0 = (k0 < kL1) ? sW2[k0 * kL2 + b] : (k0 == 30 ? sb2[b] : 0.0f);
            v1 = (k1 < kL1) ? sW2[k1 * kL2 + b] : (k1 == 30 ? sb2[b] : 0.0f);
        }
        bf0.h[e] = f2bf_rne(v0);
        bf1.h[e] = f2bf_rne(v1);
    }

    // ---- Phase A: wave computes E for its 3 q's, shares packed bf16 via LDS ----
    #pragma unroll 1
    for (int jj = 0; jj < 3; ++jj) {
        const int q = wv * 3 + jj;                    // scalar
        f32x2 E2[5];
        compute_E(q, gb, x_cont, x_cat, cont_W1, cont_b1, cont_W2, cont_b2,
                  cat_tables, E2);
        const unsigned int ep0 = pack_trunc(E2[0].x, E2[0].y);
        const unsigned int ep1 = pack_trunc(E2[1].x, E2[1].y);
        const unsigned int ep2 = pack_trunc(E2[2].x, E2[2].y);
        const unsigned int ep3 = pack_trunc(E2[3].x, E2[3].y);
        const unsigned int ep4 = pack_trunc(E2[4].x, E2[4].y);
        if (ihalf == 0) {                             // halves redundant; one writes
            unsigned int* dst = &Elds[(q * kM + b) * kES];
            *(u32x2*)(dst)     = u32x2{ep0, ep1};
            *(u32x2*)(dst + 2) = u32x2{ep2, ep3};
            dst[4] = ep4;
        }
    }
    __syncthreads();

    // ---- Phase B: h1 = [W1|sb1] @ [Ej;Ek;tok;1] via 2 MFMAs (C = 0) ----
    f32x16 acc = {};
    const unsigned int* ebase = &Elds[b * kES];
    #pragma unroll 1
    for (int ki = 0; ki < 3; ++ki) {
        const int k = __builtin_amdgcn_readfirstlane(cKset[wv * 3 + ki]);
        const unsigned int* ekp = ebase + k * kM * kES;
        const u32x2 ek01 = *(const u32x2*)ekp;        // Ek (d01),(d23)
        const u32x2 ek23 = *(const u32x2*)(ekp + 2);  // (d45),(d67)
        const unsigned int ek4 = ekp[4];              // (d89)

        #pragma unroll 1
        for (int j = 0; j <= k; ++j) {
            const int p = j * kQ - (j * (j - 1)) / 2 + (k - j);
            const unsigned int* ejp = ebase + j * kM * kES;
            const u32x2 ej01 = *(const u32x2*)ejp;
            const u32x2 ej23 = *(const u32x2*)(ejp + 2);
            const unsigned int ej4 = ejp[4];

            // tokens (p scalar -> broadcast ds_read, free)
            const u32x4 tk4 = *(const u32x4*)&Tlds[p * 8];   // tok d01..d67
            const unsigned int tk8 = Tlds[p * 8 + 4];        // tok d89

            // B-frag kstep0: slots 0..9 = Ej d0..9, 10..15 = Ek d0..5
            ABu e0;
            if (ihalf == 0) e0.u = u32x4{ej01.x, ej01.y, ej23.x, ej23.y};
            else            e0.u = u32x4{ej4, ek01.x, ek01.y, ek23.x};
            // B-frag kstep1: 16..19 = Ek d6..9, 20..29 = tok d0..9,
            //                30 = 1.0, 31 = 0
            ABu e1;
            if (ihalf == 0) e1.u = u32x4{ek23.y, ek4, tk4.x, tk4.y};
            else            e1.u = u32x4{tk4.z, tk4.w, tk8, 0x00003F80u};

            f32x16 d1 = {};
            d1 = __builtin_amdgcn_mfma_f32_32x32x16_bf16(wab0.s, e0.s, d1, 0, 0, 0);
            d1 = __builtin_amdgcn_mfma_f32_32x32x16_bf16(wab1.s, e1.s, d1, 0, 0, 0);

            D16 t; t.v = __builtin_elementwise_max(d1, (f32x16){});
            ABu hf0, hf1;                              // h1 as layer-2 B-operand
            hf0.w[0] = pack_trunc(t.q[0].x, t.q[0].y);
            hf0.w[1] = pack_trunc(t.q[0].z, t.q[0].w);
            hf0.w[2] = pack_trunc(t.q[1].x, t.q[1].y);
            hf0.w[3] = pack_trunc(t.q[1].z, t.q[1].w);
            hf1.w[0] = pack_trunc(t.q[2].x, t.q[2].y);
            hf1.w[1] = pack_trunc(t.q[2].z, t.q[2].w);
            hf1.w[2] = pack_trunc(t.q[3].x, t.q[3].y);
            hf1.w[3] = pack_trunc(t.q[3].z, t.q[3].w);

            f32x16 d2 = {};
            d2 = __builtin_amdgcn_mfma_f32_32x32x16_bf16(bf0.s, hf0.s, d2, 0, 0, 0);
            d2 = __builtin_amdgcn_mfma_f32_32x32x16_bf16(bf1.s, hf1.s, d2, 0, 0, 0);

            const float wp = out_w[p];                 // s_load
            acc += __builtin_elementwise_max(d2, (f32x16){}) * wp;
        }
    }

    // ---- epilogue: eta[b] = (1/6)*sum_r sW3[o_r]*acc[r] ----
    float etaL = 0.0f;
    if (ihalf == 0) {       // r=0..11 -> o = 0..3, 8..11, 16..19
        #pragma unroll
        for (int r = 0; r < 12; ++r)
            etaL = fmaf(acc[r], sW3[(r & 3) + 8 * (r >> 2)], etaL);
    } else {                // r=0..7 -> o = 4..7, 12..15
        #pragma unroll
        for (int r = 0; r < 8; ++r)
            etaL = fmaf(acc[r], sW3[(r & 3) + 8 * (r >> 2) + 4], etaL);
    }
    etaL += __shfl_xor(etaL, 32, 64);   // combine o-halves
    if (ihalf == 0) atomicAdd(&etab[b], etaL);
    __syncthreads();

    if (tid < kM) {
        float eta = etab[tid] * (1.0f / 6.0f) + etaConst;
        eta = fminf(fmaxf(eta, -20.0f), 20.0f);
        const int ob = blockIdx.x * kM + tid;
        out[ob] = __expf(eta) * exposure[ob];
    }
}

extern "C" void kernel_launch(void* const* d_in, const int* in_sizes, int n_in,
                              void* d_out, int out_size, void* d_ws, size_t ws_size,
                              hipStream_t stream) {
    (void)n_in; (void)out_size; (void)d_ws; (void)ws_size;
    const float* x_cont     = (const float*)d_in[0];
    const int*   x_cat      = (const int*)  d_in[1];
    const float* exposure   = (const float*)d_in[2];
    const float* cont_W1    = (const float*)d_in[3];
    const float* cont_b1    = (const float*)d_in[4];
    const float* cont_W2    = (const float*)d_in[5];
    const float* cont_b2    = (const float*)d_in[6];
    const float* cat_tables = (const float*)d_in[7];
    const float* tokens     = (const float*)d_in[8];
    const float* sW1        = (const float*)d_in[9];
    const float* sb1        = (const float*)d_in[10];
    const float* sW2        = (const float*)d_in[11];
    const float* sb2        = (const float*)d_in[12];
    const float* sW3        = (const float*)d_in[13];
    const float* sb3        = (const float*)d_in[14];
    const float* out_w      = (const float*)d_in[15];
    const float* out_b      = (const float*)d_in[16];

    const int B = in_sizes[2];        // exposure is [B]
    pin_main<<<B / kM, kBlock, 0, stream>>>(
        x_cont, x_cat, exposure, cont_W1, cont_b1, cont_W2, cont_b2,
        cat_tables, tokens, sW1, sb1, sW2, sb2, sW3, sb3, out_w, out_b,
        (float*)d_out);
}

// Round 11
// 125.923 us; speedup vs baseline: 1.1574x; 1.0909x over previous
//
#include <hip/hip_runtime.h>
#include <math.h>

typedef short bf16x8 __attribute__((ext_vector_type(8)));
typedef float f32x16 __attribute__((ext_vector_type(16)));
typedef float f32x4  __attribute__((ext_vector_type(4)));
typedef float f32x2  __attribute__((ext_vector_type(2)));
typedef unsigned int u32x4 __attribute__((ext_vector_type(4)));
typedef unsigned int u32x2 __attribute__((ext_vector_type(2)));

namespace {
constexpr int kNCont = 6, kNCat = 6, kNCategories = 100;
constexpr int kQ = 12, kD = 10, kHid = 20, kD0 = 10;
constexpr int kL1 = 30, kL2 = 20, kNPairs = 78;
constexpr int kM = 32;            // batch tile per block
constexpr int kBlock = 256;       // 4 waves
constexpr int kES = 6;            // u32 stride per [q][b] E slot (5 used + pad)
}

// Per-wave k ownership (partition of 0..11); pair counts 19/20/20/19.
__constant__ int cKset[12] = {11, 4, 1, 10, 5, 2, 9, 8, 0, 7, 6, 3};

union ABu { u32x4 u; bf16x8 s; unsigned int w[4]; unsigned short h[8]; };
union D16 { f32x16 v; f32x4 q[4]; float f[16]; };
union A12 { f32x4 q[3]; float f[12]; };

__device__ __forceinline__ unsigned int fu(float x) { return __float_as_uint(x); }
__device__ __forceinline__ unsigned short f2bf_rne(float v) {
    unsigned int x = fu(v);
    return (unsigned short)((x + 0x7FFFu + ((x >> 16) & 1u)) >> 16);
}
// pack two f32 to bf16x2 by truncation: low16 = hi(e0), high16 = hi(e1)
__device__ __forceinline__ unsigned int pack_trunc(float e0, float e1) {
    return __builtin_amdgcn_perm(fu(e1), fu(e0), 0x07060302u);
}

// Embedding E[gb,q,:] as 5 f32x2. q is SCALAR. All register indices static.
__device__ __forceinline__ void compute_E(
    int q, int gb,
    const float* __restrict__ x_cont, const int* __restrict__ x_cat,
    const float* __restrict__ cont_W1, const float* __restrict__ cont_b1,
    const float* __restrict__ cont_W2, const float* __restrict__ cont_b2,
    const float* __restrict__ cat_tables, f32x2 E2[5])
{
    if (q < kNCont) {
        const float x = x_cont[gb * kNCont + q];
        #pragma unroll
        for (int dd = 0; dd < 5; ++dd)
            E2[dd] = f32x2{cont_b2[q * kD + 2 * dd], cont_b2[q * kD + 2 * dd + 1]};
        #pragma unroll
        for (int h = 0; h < kHid; ++h) {
            const float pre = fmaf(x, cont_W1[q * kHid + h], cont_b1[q * kHid + h]);
            const float hv  = fmaxf(pre, 0.0f);
            const f32x2 hv2 = {hv, hv};
            const float* w2 = cont_W2 + (q * kHid + h) * kD;
            #pragma unroll
            for (int dd = 0; dd < 5; ++dd)
                E2[dd] = __builtin_elementwise_fma(
                    hv2, f32x2{w2[2 * dd], w2[2 * dd + 1]}, E2[dd]);
        }
    } else {
        const int c   = q - kNCont;
        const int idx = x_cat[gb * kNCat + c];
        const float* src = cat_tables + (c * kNCategories + idx) * kD;
        #pragma unroll
        for (int dd = 0; dd < 5; ++dd)
            E2[dd] = f32x2{src[2 * dd], src[2 * dd + 1]};
    }
}

__global__ __launch_bounds__(kBlock, 4) void pin_main(
    const float* __restrict__ x_cont,
    const int*   __restrict__ x_cat,
    const float* __restrict__ exposure,
    const float* __restrict__ cont_W1,
    const float* __restrict__ cont_b1,
    const float* __restrict__ cont_W2,
    const float* __restrict__ cont_b2,
    const float* __restrict__ cat_tables,
    const float* __restrict__ tokens,  // [78,10]
    const float* __restrict__ sW1,     // [30,30]
    const float* __restrict__ sb1,     // [30]
    const float* __restrict__ sW2,     // [30,20]
    const float* __restrict__ sb2,     // [20]
    const float* __restrict__ sW3,     // [20]
    const float* __restrict__ sb3,     // [1]
    const float* __restrict__ out_w,   // [78]
    const float* __restrict__ out_b,   // [1]
    float* __restrict__ out)
{
    // Packed-bf16 E table: [q][b][kES u32] (5 used). 9216 B.
    __shared__ unsigned int Elds[kQ * kM * kES];
    // Packed-bf16 tokens: [p][8 u32] (5 used; stride 8 for aligned b128). 2496 B.
    __shared__ unsigned int Tlds[kNPairs * 8];
    __shared__ float etab[kM];
    __shared__ float etaConst;

    const int tid   = threadIdx.x;
    const int lane  = tid & 63;
    const int b     = lane & 31;          // batch row / MFMA col n
    const int ihalf = lane >> 5;          // fragment k-half selector
    const int wv    = __builtin_amdgcn_readfirstlane((int)(tid >> 6));
    const int gb    = blockIdx.x * kM + b;

    if (tid < kM) etab[tid] = 0.0f;

    // ---- etaConst = out_b + sb3/6 * sum(out_w): parallel wave-0 reduce ----
    if (wv == 0) {
        float v = (lane < kNPairs) ? out_w[lane] : 0.0f;
        if (lane < kNPairs - 64) v += out_w[64 + lane];
        v += __shfl_xor(v, 1, 64);
        v += __shfl_xor(v, 2, 64);
        v += __shfl_xor(v, 4, 64);
        v += __shfl_xor(v, 8, 64);
        v += __shfl_xor(v, 16, 64);
        v += __shfl_xor(v, 32, 64);
        if (lane == 0) etaConst = out_b[0] + sb3[0] * (1.0f / 6.0f) * v;
    }

    // ---- packed-token table (coalesced; ~2 iters/thread) ----
    #pragma unroll 1
    for (int t = tid; t < kNPairs * 5; t += kBlock) {
        const int p = t / 5, dd = t - p * 5;
        Tlds[p * 8 + dd] =
            pack_trunc(tokens[p * kD0 + 2 * dd], tokens[p * kD0 + 2 * dd + 1]);
    }

    // tau: verified r7-r10 — C-reg order <-> i order for B-frag consumption.
    const int q2  = (b >> 2) & 3;
    const int tau = b + (q2 == 1 ? 4 : (q2 == 2 ? -4 : 0));

    // ---- stacked [W1a;W1b;W1c;sb1] A-frags: A[m][s] = sW1[s][tau(m)] ----
    ABu wab0, wab1;
    #pragma unroll
    for (int e = 0; e < 8; ++e) {         // kstep0: s = 8*ihalf + e
        const int s = 8 * ihalf + e;
        wab0.h[e] = f2bf_rne((tau < kL1) ? sW1[s * kL1 + tau] : 0.0f);
    }
    #pragma unroll
    for (int e = 0; e < 8; ++e) {         // kstep1: s = 16 + 8*ihalf + e
        const int s = 16 + 8 * ihalf + e;
        float v = 0.0f;
        if (tau < kL1) {
            if (s < kL1)       v = sW1[s * kL1 + tau];
            else if (s == 30)  v = sb1[tau];
        } else if (tau == 30 && s == 30) {
            v = 1.0f;                      // h1 ones-row for layer-2 sb2
        }
        wab1.h[e] = f2bf_rne(v);
    }

    // ---- layer-2 A-frags (sW2 rows o=b, k-slots i; i=30 -> sb2) ----
    ABu bf0, bf1;
    #pragma unroll
    for (int e = 0; e < 8; ++e) {
        const int k0 = ihalf * 8 + e;
        const int k1 = 16 + ihalf * 8 + e;
        float v0 = 0.0f, v1 = 0.0f;
        if (b < kL2) {
            v0 = (k0 < kL1) ? sW2[k0 * kL2 + b] : (k0 == 30 ? sb2[b] : 0.0f);
            v1 = (k1 < kL1) ? sW2[k1 * kL2 + b] : (k1 == 30 ? sb2[b] : 0.0f);
        }
        bf0.h[e] = f2bf_rne(v0);
        bf1.h[e] = f2bf_rne(v1);
    }

    // ---- Phase A: balanced q assignment (q = wv + 4*jj): each wave gets
    // at most 2 continuous-feature MLPs -> less barrier straggle ----
    #pragma unroll 1
    for (int jj = 0; jj < 3; ++jj) {
        const int q = wv + 4 * jj;                    // scalar, covers 0..11
        f32x2 E2[5];
        compute_E(q, gb, x_cont, x_cat, cont_W1, cont_b1, cont_W2, cont_b2,
                  cat_tables, E2);
        const unsigned int ep0 = pack_trunc(E2[0].x, E2[0].y);
        const unsigned int ep1 = pack_trunc(E2[1].x, E2[1].y);
        const unsigned int ep2 = pack_trunc(E2[2].x, E2[2].y);
        const unsigned int ep3 = pack_trunc(E2[3].x, E2[3].y);
        const unsigned int ep4 = pack_trunc(E2[4].x, E2[4].y);
        if (ihalf == 0) {                             // halves redundant; one writes
            unsigned int* dst = &Elds[(q * kM + b) * kES];
            *(u32x2*)(dst)     = u32x2{ep0, ep1};
            *(u32x2*)(dst + 2) = u32x2{ep2, ep3};
            dst[4] = ep4;
        }
    }
    __syncthreads();

    // ---- Phase B: h1 = [W1|sb1] @ [Ej;Ek;tok;1] via 2 MFMAs (C = 0) ----
    f32x4 acc0 = {}, acc1 = {}, acc2 = {};   // only o-rows that are read
    const unsigned int* ebase = &Elds[b * kES];
    #pragma unroll 1
    for (int ki = 0; ki < 3; ++ki) {
        const int k = __builtin_amdgcn_readfirstlane(cKset[wv * 3 + ki]);
        const unsigned int* ekp = ebase + k * kM * kES;
        const u32x2 ek01 = *(const u32x2*)ekp;        // Ek (d01),(d23)
        const u32x2 ek23 = *(const u32x2*)(ekp + 2);  // (d45),(d67)
        const unsigned int ek4 = ekp[4];              // (d89)

        #pragma unroll 2
        for (int j = 0; j <= k; ++j) {
            const int p = j * kQ - (j * (j - 1)) / 2 + (k - j);
            const unsigned int* ejp = ebase + j * kM * kES;
            const u32x2 ej01 = *(const u32x2*)ejp;
            const u32x2 ej23 = *(const u32x2*)(ejp + 2);
            const unsigned int ej4 = ejp[4];

            // tokens (p scalar -> broadcast ds_read, free)
            const u32x4 tk4 = *(const u32x4*)&Tlds[p * 8];   // tok d01..d67
            const unsigned int tk8 = Tlds[p * 8 + 4];        // tok d89

            // B-frag kstep0: slots 0..9 = Ej d0..9, 10..15 = Ek d0..5
            ABu e0;
            if (ihalf == 0) e0.u = u32x4{ej01.x, ej01.y, ej23.x, ej23.y};
            else            e0.u = u32x4{ej4, ek01.x, ek01.y, ek23.x};
            // B-frag kstep1: 16..19 = Ek d6..9, 20..29 = tok d0..9,
            //                30 = 1.0, 31 = 0
            ABu e1;
            if (ihalf == 0) e1.u = u32x4{ek23.y, ek4, tk4.x, tk4.y};
            else            e1.u = u32x4{tk4.z, tk4.w, tk8, 0x00003F80u};

            f32x16 d1 = {};
            d1 = __builtin_amdgcn_mfma_f32_32x32x16_bf16(wab0.s, e0.s, d1, 0, 0, 0);
            d1 = __builtin_amdgcn_mfma_f32_32x32x16_bf16(wab1.s, e1.s, d1, 0, 0, 0);

            D16 t; t.v = __builtin_elementwise_max(d1, (f32x16){});
            ABu hf0, hf1;                              // h1 as layer-2 B-operand
            hf0.w[0] = pack_trunc(t.q[0].x, t.q[0].y);
            hf0.w[1] = pack_trunc(t.q[0].z, t.q[0].w);
            hf0.w[2] = pack_trunc(t.q[1].x, t.q[1].y);
            hf0.w[3] = pack_trunc(t.q[1].z, t.q[1].w);
            hf1.w[0] = pack_trunc(t.q[2].x, t.q[2].y);
            hf1.w[1] = pack_trunc(t.q[2].z, t.q[2].w);
            hf1.w[2] = pack_trunc(t.q[3].x, t.q[3].y);
            hf1.w[3] = pack_trunc(t.q[3].z, t.q[3].w);

            f32x16 d2 = {};
            d2 = __builtin_amdgcn_mfma_f32_32x32x16_bf16(bf0.s, hf0.s, d2, 0, 0, 0);
            d2 = __builtin_amdgcn_mfma_f32_32x32x16_bf16(bf1.s, hf1.s, d2, 0, 0, 0);

            // acc only regs 0..11 (regs 12..15 are never read downstream)
            const float wp = out_w[p];                 // s_load
            const f32x4 wp4 = {wp, wp, wp, wp};
            const f32x4 z4 = {};
            D16 r2; r2.v = d2;
            acc0 = __builtin_elementwise_fma(
                __builtin_elementwise_max(r2.q[0], z4), wp4, acc0);
            acc1 = __builtin_elementwise_fma(
                __builtin_elementwise_max(r2.q[1], z4), wp4, acc1);
            acc2 = __builtin_elementwise_fma(
                __builtin_elementwise_max(r2.q[2], z4), wp4, acc2);
        }
    }

    // ---- epilogue: eta[b] = (1/6)*sum_r sW3[o_r]*acc[r] ----
    A12 av; av.q[0] = acc0; av.q[1] = acc1; av.q[2] = acc2;
    float etaL = 0.0f;
    if (ihalf == 0) {       // r=0..11 -> o = 0..3, 8..11, 16..19
        #pragma unroll
        for (int r = 0; r < 12; ++r)
            etaL = fmaf(av.f[r], sW3[(r & 3) + 8 * (r >> 2)], etaL);
    } else {                // r=0..7 -> o = 4..7, 12..15
        #pragma unroll
        for (int r = 0; r < 8; ++r)
            etaL = fmaf(av.f[r], sW3[(r & 3) + 8 * (r >> 2) + 4], etaL);
    }
    etaL += __shfl_xor(etaL, 32, 64);   // combine o-halves
    if (ihalf == 0) atomicAdd(&etab[b], etaL);
    __syncthreads();

    if (tid < kM) {
        float eta = etab[tid] * (1.0f / 6.0f) + etaConst;
        eta = fminf(fmaxf(eta, -20.0f), 20.0f);
        const int ob = blockIdx.x * kM + tid;
        out[ob] = __expf(eta) * exposure[ob];
    }
}

extern "C" void kernel_launch(void* const* d_in, const int* in_sizes, int n_in,
                              void* d_out, int out_size, void* d_ws, size_t ws_size,
                              hipStream_t stream) {
    (void)n_in; (void)out_size; (void)d_ws; (void)ws_size;
    const float* x_cont     = (const float*)d_in[0];
    const int*   x_cat      = (const int*)  d_in[1];
    const float* exposure   = (const float*)d_in[2];
    const float* cont_W1    = (const float*)d_in[3];
    const float* cont_b1    = (const float*)d_in[4];
    const float* cont_W2    = (const float*)d_in[5];
    const float* cont_b2    = (const float*)d_in[6];
    const float* cat_tables = (const float*)d_in[7];
    const float* tokens     = (const float*)d_in[8];
    const float* sW1        = (const float*)d_in[9];
    const float* sb1        = (const float*)d_in[10];
    const float* sW2        = (const float*)d_in[11];
    const float* sb2        = (const float*)d_in[12];
    const float* sW3        = (const float*)d_in[13];
    const float* sb3        = (const float*)d_in[14];
    const float* out_w      = (const float*)d_in[15];
    const float* out_b      = (const float*)d_in[16];

    const int B = in_sizes[2];        // exposure is [B]
    pin_main<<<B / kM, kBlock, 0, stream>>>(
        x_cont, x_cat, exposure, cont_W1, cont_b1, cont_W2, cont_b2,
        cat_tables, tokens, sW1, sb1, sW2, sb2, sW3, sb3, out_w, out_b,
        (float*)d_out);
}